// Round 2
// baseline (690.195 us; speedup 1.0000x reference)
//
#include <hip/hip_runtime.h>

#define NN 23552   // total nodes
#define BBATCH 1024
#define PP 23      // nodes per frame
#define FF 14
#define DD 256
#define HHEADS 4
#define DHH 64
#define CC 23

typedef __attribute__((ext_vector_type(8))) short bf16x8;
typedef __attribute__((ext_vector_type(4))) float f32x4;

#define GLOAD16(gp, lp) __builtin_amdgcn_global_load_lds( \
    (const __attribute__((address_space(1))) void*)(gp),  \
    (__attribute__((address_space(3))) void*)(lp), 16, 0, 0)

__device__ __forceinline__ short f2bf_rne(float v) {
    unsigned u = __float_as_uint(v);
    unsigned r = (u + 0x7FFFu + ((u >> 16) & 1u)) >> 16;
    return (short)(unsigned short)r;
}
__device__ __forceinline__ float bf2f(short s) {
    return __uint_as_float(((unsigned)(unsigned short)s) << 16);
}

// ---------------- weight prep: Wt_hi/Wt_lo [l][n=512][k=256] bf16, transposed ----------------
__global__ __launch_bounds__(256) void k_prep_w(const float* __restrict__ Wl,
    const float* __restrict__ Wr, short* __restrict__ Wth, short* __restrict__ Wtl)
{
    int bid = blockIdx.x;            // l*512 + n
    int ll = bid >> 9, n = bid & 511;
    int t = threadIdx.x;             // k
    const float* W = (n < 256) ? (Wl + (size_t)ll * 65536) : (Wr + (size_t)ll * 65536);
    int nc = n & 255;
    float v = W[(size_t)t * 256 + nc];
    short hi = f2bf_rne(v);
    short lo = f2bf_rne(v - bf2f(hi));
    size_t o = (size_t)bid * 256 + t;
    Wth[o] = hi; Wtl[o] = lo;
}

// ---------------- input projection: h = x @ W_in + b_in (+ bf16 hi/lo split) ----------------
__global__ __launch_bounds__(256) void k_in_proj(const float* __restrict__ x,
    const float* __restrict__ Win, const float* __restrict__ bin,
    float* __restrict__ h, short* __restrict__ Ah, short* __restrict__ Al)
{
    __shared__ float xs[16][FF];
    int t = threadIdx.x;
    int r0 = blockIdx.x * 16;
    for (int idx = t; idx < 16 * FF; idx += 256) {
        int r = idx / FF, f = idx - r * FF;
        xs[r][f] = x[(r0 + r) * FF + f];
    }
    __syncthreads();
    float w[FF];
#pragma unroll
    for (int f = 0; f < FF; ++f) w[f] = Win[f * DD + t];
    float bb = bin[t];
#pragma unroll
    for (int r = 0; r < 16; ++r) {
        float acc = bb;
#pragma unroll
        for (int f = 0; f < FF; ++f) acc = fmaf(xs[r][f], w[f], acc);
        size_t gi = (size_t)(r0 + r) * DD + t;
        h[gi] = acc;
        short hi = f2bf_rne(acc);
        Ah[gi] = hi;
        Al[gi] = f2bf_rne(acc - bf2f(hi));
    }
}

// ---------------- MFMA projection: [hl|hr] = A @ Wt^T with bf16 hi/lo split ----------------
// A_hi/A_lo: [23552][256] bf16; B (Wt): [512][256] bf16 (row n, col k).
// Tile 128x128, BK=64, 4 waves (2x2), each wave 64x64 via 4x4 frags of 16x16x32.
__global__ __launch_bounds__(256) void k_gemm(
    const short* __restrict__ Ah, const short* __restrict__ Al,
    const short* __restrict__ Bh, const short* __restrict__ Bl,
    float* __restrict__ hl, float* __restrict__ hr)
{
    __shared__ short As_h[128 * 64], As_l[128 * 64], Bs_h[128 * 64], Bs_l[128 * 64];
    int t = threadIdx.x;
    int bm = blockIdx.x;            // 0..183
    int bn = blockIdx.y;            // 0..3
    int arow0 = bm * 128;
    int brow0 = bn * 128;

    int l = t & 63, w = t >> 6;
    int wm = w >> 1, wn = w & 1;
    int lr = l & 15;
    int swz = (l & 7) << 4;               // frag-read swizzle (row&7 == l&7)
    int kb0 = (l >> 4) * 16;              // byte offset of this lane's k-block

    // staging: thread t stages 16B of row srow (within each 32-row group)
    int srow = t >> 3;
    int scol = ((t & 7) ^ (srow & 7)) * 8;   // pre-swizzled source k element
    int ldst = srow * 64 + (t & 7) * 8;      // linear LDS dst (elements)

    const short* gA_h = Ah + (size_t)(arow0 + srow) * 256 + scol;
    const short* gA_l = Al + (size_t)(arow0 + srow) * 256 + scol;
    const short* gB_h = Bh + (size_t)(brow0 + srow) * 256 + scol;
    const short* gB_l = Bl + (size_t)(brow0 + srow) * 256 + scol;

    f32x4 acc[4][4];
#pragma unroll
    for (int i = 0; i < 4; ++i)
#pragma unroll
        for (int j = 0; j < 4; ++j) acc[i][j] = (f32x4)0.0f;

    for (int kt = 0; kt < 256; kt += 64) {
        if (kt) __syncthreads();
#pragma unroll
        for (int c = 0; c < 4; ++c) {
            size_t go = (size_t)(c * 32) * 256 + kt;
            int lo2 = c * 2048 + ldst;
            GLOAD16(gA_h + go, As_h + lo2);
            GLOAD16(gA_l + go, As_l + lo2);
            GLOAD16(gB_h + go, Bs_h + lo2);
            GLOAD16(gB_l + go, Bs_l + lo2);
        }
        __syncthreads();

#pragma unroll
        for (int kk = 0; kk < 2; ++kk) {
            int kcol = (kk * 64 + kb0) ^ swz;
            bf16x8 a_h[4], a_l[4], b_h[4], b_l[4];
#pragma unroll
            for (int mt = 0; mt < 4; ++mt) {
                int off = (wm * 64 + mt * 16 + lr) * 128 + kcol;
                a_h[mt] = *(const bf16x8*)((const char*)As_h + off);
                a_l[mt] = *(const bf16x8*)((const char*)As_l + off);
            }
#pragma unroll
            for (int nt = 0; nt < 4; ++nt) {
                int off = (wn * 64 + nt * 16 + lr) * 128 + kcol;
                b_h[nt] = *(const bf16x8*)((const char*)Bs_h + off);
                b_l[nt] = *(const bf16x8*)((const char*)Bs_l + off);
            }
#pragma unroll
            for (int mt = 0; mt < 4; ++mt)
#pragma unroll
                for (int nt = 0; nt < 4; ++nt) {
                    acc[mt][nt] = __builtin_amdgcn_mfma_f32_16x16x32_bf16(
                        a_h[mt], b_h[nt], acc[mt][nt], 0, 0, 0);
                    acc[mt][nt] = __builtin_amdgcn_mfma_f32_16x16x32_bf16(
                        a_h[mt], b_l[nt], acc[mt][nt], 0, 0, 0);
                    acc[mt][nt] = __builtin_amdgcn_mfma_f32_16x16x32_bf16(
                        a_l[mt], b_h[nt], acc[mt][nt], 0, 0, 0);
                }
        }
    }

    float* outp = (bn < 2) ? hl : hr;
    int gc0 = brow0 - ((bn < 2) ? 0 : 256) + wn * 64;
#pragma unroll
    for (int mt = 0; mt < 4; ++mt)
#pragma unroll
        for (int nt = 0; nt < 4; ++nt)
#pragma unroll
            for (int r2 = 0; r2 < 4; ++r2) {
                int gr = arow0 + wm * 64 + mt * 16 + (l >> 4) * 4 + r2;
                int gc = gc0 + nt * 16 + lr;
                outp[(size_t)gr * 256 + gc] = acc[mt][nt][r2];
            }
}

// ---------------- dense per-frame GATv2 attention (complete digraph) ----------------
__global__ __launch_bounds__(512) void k_edges(const float* __restrict__ hl,
    const float* __restrict__ hr, const float* __restrict__ att,
    float* __restrict__ h, short* __restrict__ Ah, short* __restrict__ Al)
{
    __shared__ float sl[PP][DD + 4];
    __shared__ float sr[PP][DD + 4];
    __shared__ float S[PP][PP][HHEADS];
    __shared__ float satt[DD];
    int t = threadIdx.x;
    int base = blockIdx.x * PP;

    if (t < DD) satt[t] = att[t];
    for (int idx = t; idx < PP * 64; idx += 512) {
        int r = idx >> 6, c4 = (idx & 63) * 4;
        *(float4*)&sl[r][c4] = *(const float4*)&hl[(size_t)(base + r) * DD + c4];
        *(float4*)&sr[r][c4] = *(const float4*)&hr[(size_t)(base + r) * DD + c4];
    }
    __syncthreads();

    // scores: one thread per (dst i, src j) pair, all 4 heads, float4 LDS reads
    for (int p = t; p < PP * PP; p += 512) {
        int i = p / PP, j = p - i * PP;
        float acch[HHEADS];
#pragma unroll
        for (int hh = 0; hh < HHEADS; ++hh) {
            float a = 0.f;
#pragma unroll
            for (int k4 = 0; k4 < 16; ++k4) {
                int c = hh * DHH + k4 * 4;
                float4 vl = *(const float4*)&sl[j][c];
                float4 vr = *(const float4*)&sr[i][c];
                float4 va = *(const float4*)&satt[c];
                float v0 = vl.x + vr.x; v0 = (v0 >= 0.f) ? v0 : 0.2f * v0;
                float v1 = vl.y + vr.y; v1 = (v1 >= 0.f) ? v1 : 0.2f * v1;
                float v2 = vl.z + vr.z; v2 = (v2 >= 0.f) ? v2 : 0.2f * v2;
                float v3 = vl.w + vr.w; v3 = (v3 >= 0.f) ? v3 : 0.2f * v3;
                a = fmaf(va.x, v0, a);
                a = fmaf(va.y, v1, a);
                a = fmaf(va.z, v2, a);
                a = fmaf(va.w, v3, a);
            }
            acch[hh] = a;
        }
#pragma unroll
        for (int hh = 0; hh < HHEADS; ++hh)
            S[i][j][hh] = (i == j) ? -1e30f : acch[hh];
    }
    __syncthreads();

    // softmax over sources j for each (i, head); recompute exp (no reg array)
    if (t < PP * HHEADS) {
        int i = t >> 2, hh = t & 3;
        float m = -1e30f;
#pragma unroll
        for (int j = 0; j < PP; ++j) m = fmaxf(m, S[i][j][hh]);
        float s = 0.f;
#pragma unroll
        for (int j = 0; j < PP; ++j) s += expf(S[i][j][hh] - m);
        float inv = 1.f / s;
#pragma unroll
        for (int j = 0; j < PP; ++j) S[i][j][hh] = expf(S[i][j][hh] - m) * inv;
    }
    __syncthreads();

    // aggregate + residual + elu + bf16 split; thread = (channel c, i-parity)
    int c = t & 255;
    int ip = t >> 8;
    int hh = c >> 6;   // wave-uniform
    float slc[PP];
#pragma unroll
    for (int j = 0; j < PP; ++j) slc[j] = sl[j][c];
    for (int i = ip; i < PP; i += 2) {
        float acc = 0.f;
#pragma unroll
        for (int j = 0; j < PP; ++j) acc = fmaf(S[i][j][hh], slc[j], acc);
        size_t gi = (size_t)(base + i) * DD + c;
        float res = acc + h[gi];
        float outv = (res > 0.f) ? res : expm1f(res);
        h[gi] = outv;
        short hi = f2bf_rne(outv);
        Ah[gi] = hi;
        Al[gi] = f2bf_rne(outv - bf2f(hi));
    }
}

// ---------------- mean readout per frame ----------------
__global__ __launch_bounds__(256) void k_readout(const float* __restrict__ h,
    float* __restrict__ g)
{
    int b = blockIdx.x, t = threadIdx.x;
    const float* hp = h + (size_t)b * PP * DD + t;
    float acc = 0.f;
#pragma unroll
    for (int p = 0; p < PP; ++p) acc += hp[p * DD];
    g[b * DD + t] = acc * (1.0f / 23.0f);
}

// ---------------- EB[c] = E_recv[c] @ Ws1[256:512,:]  (graph-independent) ----------------
__global__ __launch_bounds__(256) void k_eb(const float* __restrict__ E,
    const float* __restrict__ Ws1, float* __restrict__ EB)
{
    int c = blockIdx.x, t = threadIdx.x;
    float acc = 0.f;
    for (int k = 0; k < DD; ++k)
        acc = fmaf(E[c * DD + k], Ws1[(DD + k) * DD + t], acc);
    EB[c * DD + t] = acc;
}

// ---------------- per-graph head ----------------
__global__ __launch_bounds__(256) void k_head(const float* __restrict__ g,
    const float* __restrict__ Wr1, const float* __restrict__ br1,
    const float* __restrict__ Wr2, const float* __restrict__ br2,
    const float* __restrict__ Ws1, const float* __restrict__ bs1,
    const float* __restrict__ Ws2, const float* __restrict__ bs2,
    const float* __restrict__ EB, float* __restrict__ out)
{
    __shared__ float gs[DD], t1[DD], gtop[DD], logits[CC], probs[CC], red[4];
    int b = blockIdx.x, t = threadIdx.x;
    gs[t] = g[b * DD + t];
    __syncthreads();

    float a1 = 0.f, a2 = 0.f;
    for (int k = 0; k < DD; ++k) {
        float gv = gs[k];
        a1 = fmaf(gv, Wr1[k * DD + t], a1);
        a2 = fmaf(gv, Ws1[k * DD + t], a2);
    }
    t1[t] = fmaxf(a1 + br1[t], 0.f);
    gtop[t] = a2 + bs1[t];
    __syncthreads();

    if (t < CC) {
        float acc = br2[t];
        for (int d = 0; d < DD; ++d) acc = fmaf(t1[d], Wr2[d * CC + t], acc);
        logits[t] = acc;
    }
    __syncthreads();
    if (t < CC) {
        float m = -1e30f;
        for (int c = 0; c < CC; ++c) m = fmaxf(m, logits[c]);
        float s = 0.f;
        for (int c = 0; c < CC; ++c) s += expf(logits[c] - m);
        probs[t] = expf(logits[t] - m) / s;
    }
    __syncthreads();

    float wd = Ws2[t];
    float gt = gtop[t];
    float acc = 0.f;
#pragma unroll
    for (int c = 0; c < CC; ++c) {
        float s1 = fmaxf(gt + EB[c * DD + t], 0.f);
        acc = fmaf(probs[c], s1, acc);
    }
    acc *= wd;
#pragma unroll
    for (int off = 32; off > 0; off >>= 1) acc += __shfl_down(acc, off, 64);
    if ((t & 63) == 0) red[t >> 6] = acc;
    __syncthreads();
    if (t == 0) out[b] = red[0] + red[1] + red[2] + red[3] + bs2[0];
}

extern "C" void kernel_launch(void* const* d_in, const int* in_sizes, int n_in,
                              void* d_out, int out_size, void* d_ws, size_t ws_size,
                              hipStream_t stream)
{
    const float* x     = (const float*)d_in[0];
    const float* Win   = (const float*)d_in[3];
    const float* bin   = (const float*)d_in[4];
    const float* Wl    = (const float*)d_in[5];
    const float* Wr    = (const float*)d_in[6];
    const float* att   = (const float*)d_in[7];
    const float* Wr1   = (const float*)d_in[8];
    const float* br1   = (const float*)d_in[9];
    const float* Wr2   = (const float*)d_in[10];
    const float* br2   = (const float*)d_in[11];
    const float* Erecv = (const float*)d_in[12];
    const float* Ws1   = (const float*)d_in[13];
    const float* bs1   = (const float*)d_in[14];
    const float* Ws2   = (const float*)d_in[15];
    const float* bs2   = (const float*)d_in[16];
    float* out = (float*)d_out;

    // workspace layout (floats first, then bf16/shorts; all 16B aligned)
    float* h   = (float*)d_ws;                        // [NN, DD]
    float* hl  = h  + (size_t)NN * DD;
    float* hr  = hl + (size_t)NN * DD;
    float* g   = hr + (size_t)NN * DD;                // [B, DD]
    float* EB  = g  + (size_t)BBATCH * DD;            // [CC, DD]
    short* Ah  = (short*)(EB + (size_t)CC * DD);      // [NN, DD] bf16 hi
    short* Al  = Ah + (size_t)NN * DD;                // bf16 lo
    short* Wth = Al + (size_t)NN * DD;                // [3][512][256]
    short* Wtl = Wth + (size_t)3 * 512 * 256;

    k_prep_w<<<dim3(3 * 512), dim3(256), 0, stream>>>(Wl, Wr, Wth, Wtl);
    k_in_proj<<<dim3(NN / 16), dim3(256), 0, stream>>>(x, Win, bin, h, Ah, Al);

    for (int l = 0; l < 3; ++l) {
        k_gemm<<<dim3(184, 4), dim3(256), 0, stream>>>(Ah, Al,
            Wth + (size_t)l * 512 * 256, Wtl + (size_t)l * 512 * 256, hl, hr);
        k_edges<<<dim3(BBATCH), dim3(512), 0, stream>>>(hl, hr,
            att + (size_t)l * DD, h, Ah, Al);
    }

    k_readout<<<dim3(BBATCH), dim3(256), 0, stream>>>(h, g);
    k_eb<<<dim3(CC), dim3(256), 0, stream>>>(Erecv, Ws1, EB);
    k_head<<<dim3(BBATCH), dim3(256), 0, stream>>>(g, Wr1, br1, Wr2, br2,
                                                   Ws1, bs1, Ws2, bs2, EB, out);
}

// Round 3
// 464.137 us; speedup vs baseline: 1.4870x; 1.4870x over previous
//
#include <hip/hip_runtime.h>

#define NN 23552   // total nodes
#define BBATCH 1024
#define PP 23      // nodes per frame
#define FF 14
#define DD 256
#define CC 23

typedef __attribute__((ext_vector_type(8))) short bf16x8;
typedef __attribute__((ext_vector_type(4))) float f32x4;

__device__ __forceinline__ short f2bf_rne(float v) {
    unsigned u = __float_as_uint(v);
    unsigned r = (u + 0x7FFFu + ((u >> 16) & 1u)) >> 16;
    return (short)(unsigned short)r;
}
__device__ __forceinline__ float bf2f(short s) {
    return __uint_as_float(((unsigned)(unsigned short)s) << 16);
}

// ---------------- weight prep: Wt_hi/Wt_lo [l][n=512][k=256] bf16, transposed ----------------
__global__ __launch_bounds__(256) void k_prep_w(const float* __restrict__ Wl,
    const float* __restrict__ Wr, short* __restrict__ Wth, short* __restrict__ Wtl)
{
    int bid = blockIdx.x;            // l*512 + n
    int ll = bid >> 9, n = bid & 511;
    int t = threadIdx.x;             // k
    const float* W = (n < 256) ? (Wl + (size_t)ll * 65536) : (Wr + (size_t)ll * 65536);
    int nc = n & 255;
    float v = W[(size_t)t * 256 + nc];
    short hi = f2bf_rne(v);
    short lo = f2bf_rne(v - bf2f(hi));
    size_t o = (size_t)bid * 256 + t;
    Wth[o] = hi; Wtl[o] = lo;
}

// ---------------- input projection: h = x @ W_in + b_in -> bf16 hi/lo only ----------------
__global__ __launch_bounds__(256) void k_in_proj(const float* __restrict__ x,
    const float* __restrict__ Win, const float* __restrict__ bin,
    short* __restrict__ Ah, short* __restrict__ Al)
{
    __shared__ float xs[16][FF];
    int t = threadIdx.x;
    int r0 = blockIdx.x * 16;
    for (int idx = t; idx < 16 * FF; idx += 256) {
        int r = idx / FF, f = idx - r * FF;
        xs[r][f] = x[(r0 + r) * FF + f];
    }
    __syncthreads();
    float w[FF];
#pragma unroll
    for (int f = 0; f < FF; ++f) w[f] = Win[f * DD + t];
    float bb = bin[t];
#pragma unroll
    for (int r = 0; r < 16; ++r) {
        float acc = bb;
#pragma unroll
        for (int f = 0; f < FF; ++f) acc = fmaf(xs[r][f], w[f], acc);
        size_t gi = (size_t)(r0 + r) * DD + t;
        short hi = f2bf_rne(acc);
        Ah[gi] = hi;
        Al[gi] = f2bf_rne(acc - bf2f(hi));
    }
}

// ---------------- fused per-frame GATv2 layer ----------------
// Per block = 1 frame: MFMA GEMM [32pad x 512] = A(23x256) @ [Wl|Wr]^T with
// bf16 hi/lo 3-term split (A-frags direct from global, B-frags from L2-resident
// transposed weights), acc -> LDS hl/hr f32, then dense scores/softmax/aggregate.
__global__ __launch_bounds__(512, 4) void k_layer(
    short* __restrict__ Ah, short* __restrict__ Al,
    const short* __restrict__ Bh, const short* __restrict__ Bl,
    const float* __restrict__ att)
{
    __shared__ float sl[PP][DD + 1];     // hl (messages): stride 257 = conflict-free
    __shared__ float sr[PP][DD + 1];     // hr (dst term)
    __shared__ float S[PP][PP][4];
    __shared__ float satt[DD];

    int t = threadIdx.x;
    int base = blockIdx.x * PP;
    if (t < DD) satt[t] = att[t];

    // ---- GEMM phase: wave w owns output cols n0..n0+63 over rows 0..31 ----
    int l = t & 63;
    int w = t >> 6;
    int n0 = w * 64;
    int lr = l & 15;
    int lk = (l >> 4) * 8;

    const short* pAh = Ah + (size_t)(base + lr) * DD + lk;
    const short* pAl = Al + (size_t)(base + lr) * DD + lk;
    const short* pBh = Bh + (size_t)(n0 + lr) * DD + lk;
    const short* pBl = Bl + (size_t)(n0 + lr) * DD + lk;

    f32x4 acc[2][4];
#pragma unroll
    for (int mt = 0; mt < 2; ++mt)
#pragma unroll
        for (int nt = 0; nt < 4; ++nt) acc[mt][nt] = (f32x4)0.0f;

#pragma unroll
    for (int k0 = 0; k0 < DD; k0 += 32) {
        bf16x8 ah0 = *(const bf16x8*)(pAh + k0);
        bf16x8 ah1 = *(const bf16x8*)(pAh + 16 * DD + k0);   // pad rows >=23: garbage ok (masked)
        bf16x8 al0 = *(const bf16x8*)(pAl + k0);
        bf16x8 al1 = *(const bf16x8*)(pAl + 16 * DD + k0);
#pragma unroll
        for (int nt = 0; nt < 4; ++nt) {
            bf16x8 bh = *(const bf16x8*)(pBh + nt * 16 * DD + k0);
            bf16x8 bl = *(const bf16x8*)(pBl + nt * 16 * DD + k0);
            acc[0][nt] = __builtin_amdgcn_mfma_f32_16x16x32_bf16(ah0, bh, acc[0][nt], 0, 0, 0);
            acc[0][nt] = __builtin_amdgcn_mfma_f32_16x16x32_bf16(ah0, bl, acc[0][nt], 0, 0, 0);
            acc[0][nt] = __builtin_amdgcn_mfma_f32_16x16x32_bf16(al0, bh, acc[0][nt], 0, 0, 0);
            acc[1][nt] = __builtin_amdgcn_mfma_f32_16x16x32_bf16(ah1, bh, acc[1][nt], 0, 0, 0);
            acc[1][nt] = __builtin_amdgcn_mfma_f32_16x16x32_bf16(ah1, bl, acc[1][nt], 0, 0, 0);
            acc[1][nt] = __builtin_amdgcn_mfma_f32_16x16x32_bf16(al1, bh, acc[1][nt], 0, 0, 0);
        }
    }

    // scatter acc -> LDS hl/hr (f32), drop pad rows
#pragma unroll
    for (int mt = 0; mt < 2; ++mt) {
        int row = mt * 16 + (l >> 4) * 4;
#pragma unroll
        for (int nt = 0; nt < 4; ++nt) {
            int col = n0 + nt * 16 + lr;        // wave-uniform hl/hr split
            float* dst = (col < 256) ? &sl[0][0] : &sr[0][0];
            int cc = col & 255;
#pragma unroll
            for (int r2 = 0; r2 < 4; ++r2) {
                if (row + r2 < PP) dst[(row + r2) * (DD + 1) + cc] = acc[mt][nt][r2];
            }
        }
    }
    __syncthreads();

    // ---- scores: thread per (dst i, src j), 4 heads interleaved, scalar reads ----
    for (int p = t; p < PP * PP; p += 512) {
        int i = p / PP, j = p - i * PP;
        float s0 = 0.f, s1 = 0.f, s2 = 0.f, s3 = 0.f;
#pragma unroll 16
        for (int k = 0; k < 64; ++k) {
            float v0 = sl[j][k]       + sr[i][k];
            float v1 = sl[j][64 + k]  + sr[i][64 + k];
            float v2 = sl[j][128 + k] + sr[i][128 + k];
            float v3 = sl[j][192 + k] + sr[i][192 + k];
            v0 = (v0 >= 0.f) ? v0 : 0.2f * v0;
            v1 = (v1 >= 0.f) ? v1 : 0.2f * v1;
            v2 = (v2 >= 0.f) ? v2 : 0.2f * v2;
            v3 = (v3 >= 0.f) ? v3 : 0.2f * v3;
            s0 = fmaf(satt[k], v0, s0);
            s1 = fmaf(satt[64 + k], v1, s1);
            s2 = fmaf(satt[128 + k], v2, s2);
            s3 = fmaf(satt[192 + k], v3, s3);
        }
        bool diag = (i == j);
        S[i][j][0] = diag ? -1e30f : s0;
        S[i][j][1] = diag ? -1e30f : s1;
        S[i][j][2] = diag ? -1e30f : s2;
        S[i][j][3] = diag ? -1e30f : s3;
    }
    __syncthreads();

    // ---- softmax over j for each (i, head) ----
    if (t < PP * 4) {
        int i = t >> 2, hh = t & 3;
        float m = -1e30f;
#pragma unroll
        for (int j = 0; j < PP; ++j) m = fmaxf(m, S[i][j][hh]);
        float s = 0.f;
#pragma unroll
        for (int j = 0; j < PP; ++j) s += expf(S[i][j][hh] - m);
        float inv = 1.f / s;
#pragma unroll
        for (int j = 0; j < PP; ++j) S[i][j][hh] = expf(S[i][j][hh] - m) * inv;
    }
    __syncthreads();

    // ---- aggregate + residual + elu -> write back bf16 hi/lo ----
    int c = t & 255;
    int ip = t >> 8;
    int hh = c >> 6;   // wave-uniform
    float slc[PP];
#pragma unroll
    for (int j = 0; j < PP; ++j) slc[j] = sl[j][c];
    for (int i = ip; i < PP; i += 2) {
        float accv = 0.f;
#pragma unroll
        for (int j = 0; j < PP; ++j) accv = fmaf(S[i][j][hh], slc[j], accv);
        size_t gi = (size_t)(base + i) * DD + c;
        float prev = bf2f(Ah[gi]) + bf2f(Al[gi]);
        float res = accv + prev;
        float outv = (res > 0.f) ? res : expm1f(res);
        short hi = f2bf_rne(outv);
        Ah[gi] = hi;
        Al[gi] = f2bf_rne(outv - bf2f(hi));
    }
}

// ---------------- mean readout per frame (from bf16 hi/lo) ----------------
__global__ __launch_bounds__(256) void k_readout(const short* __restrict__ Ah,
    const short* __restrict__ Al, float* __restrict__ g)
{
    int b = blockIdx.x, t = threadIdx.x;
    const short* pa = Ah + (size_t)b * PP * DD + t;
    const short* pl = Al + (size_t)b * PP * DD + t;
    float acc = 0.f;
#pragma unroll
    for (int p = 0; p < PP; ++p) acc += bf2f(pa[p * DD]) + bf2f(pl[p * DD]);
    g[b * DD + t] = acc * (1.0f / 23.0f);
}

// ---------------- EB[c] = E_recv[c] @ Ws1[256:512,:]  (graph-independent) ----------------
__global__ __launch_bounds__(256) void k_eb(const float* __restrict__ E,
    const float* __restrict__ Ws1, float* __restrict__ EB)
{
    int c = blockIdx.x, t = threadIdx.x;
    float acc = 0.f;
    for (int k = 0; k < DD; ++k)
        acc = fmaf(E[c * DD + k], Ws1[(DD + k) * DD + t], acc);
    EB[c * DD + t] = acc;
}

// ---------------- per-graph head ----------------
__global__ __launch_bounds__(256) void k_head(const float* __restrict__ g,
    const float* __restrict__ Wr1, const float* __restrict__ br1,
    const float* __restrict__ Wr2, const float* __restrict__ br2,
    const float* __restrict__ Ws1, const float* __restrict__ bs1,
    const float* __restrict__ Ws2, const float* __restrict__ bs2,
    const float* __restrict__ EB, float* __restrict__ out)
{
    __shared__ float gs[DD], t1[DD], gtop[DD], logits[CC], probs[CC], red[4];
    int b = blockIdx.x, t = threadIdx.x;
    gs[t] = g[b * DD + t];
    __syncthreads();

    float a1 = 0.f, a2 = 0.f;
    for (int k = 0; k < DD; ++k) {
        float gv = gs[k];
        a1 = fmaf(gv, Wr1[k * DD + t], a1);
        a2 = fmaf(gv, Ws1[k * DD + t], a2);
    }
    t1[t] = fmaxf(a1 + br1[t], 0.f);
    gtop[t] = a2 + bs1[t];
    __syncthreads();

    if (t < CC) {
        float acc = br2[t];
        for (int d = 0; d < DD; ++d) acc = fmaf(t1[d], Wr2[d * CC + t], acc);
        logits[t] = acc;
    }
    __syncthreads();
    if (t < CC) {
        float m = -1e30f;
        for (int c = 0; c < CC; ++c) m = fmaxf(m, logits[c]);
        float s = 0.f;
        for (int c = 0; c < CC; ++c) s += expf(logits[c] - m);
        probs[t] = expf(logits[t] - m) / s;
    }
    __syncthreads();

    float wd = Ws2[t];
    float gt = gtop[t];
    float acc = 0.f;
#pragma unroll
    for (int c = 0; c < CC; ++c) {
        float s1 = fmaxf(gt + EB[c * DD + t], 0.f);
        acc = fmaf(probs[c], s1, acc);
    }
    acc *= wd;
#pragma unroll
    for (int off = 32; off > 0; off >>= 1) acc += __shfl_down(acc, off, 64);
    if ((t & 63) == 0) red[t >> 6] = acc;
    __syncthreads();
    if (t == 0) out[b] = red[0] + red[1] + red[2] + red[3] + bs2[0];
}

extern "C" void kernel_launch(void* const* d_in, const int* in_sizes, int n_in,
                              void* d_out, int out_size, void* d_ws, size_t ws_size,
                              hipStream_t stream)
{
    const float* x     = (const float*)d_in[0];
    const float* Win   = (const float*)d_in[3];
    const float* bin   = (const float*)d_in[4];
    const float* Wl    = (const float*)d_in[5];
    const float* Wr    = (const float*)d_in[6];
    const float* att   = (const float*)d_in[7];
    const float* Wr1   = (const float*)d_in[8];
    const float* br1   = (const float*)d_in[9];
    const float* Wr2   = (const float*)d_in[10];
    const float* br2   = (const float*)d_in[11];
    const float* Erecv = (const float*)d_in[12];
    const float* Ws1   = (const float*)d_in[13];
    const float* bs1   = (const float*)d_in[14];
    const float* Ws2   = (const float*)d_in[15];
    const float* bs2   = (const float*)d_in[16];
    float* out = (float*)d_out;

    // workspace: Ah/Al first so pad-row overreads (last frame, rows 23..31)
    // land in allocated memory (Al then Wth).
    short* Ah  = (short*)d_ws;                        // [NN][DD] bf16 hi
    short* Al  = Ah + (size_t)NN * DD;                // [NN][DD] bf16 lo
    short* Wth = Al + (size_t)NN * DD;                // [3][512][256]
    short* Wtl = Wth + (size_t)3 * 512 * 256;
    float* g   = (float*)(Wtl + (size_t)3 * 512 * 256);  // [B][DD]
    float* EB  = g + (size_t)BBATCH * DD;             // [CC][DD]

    k_prep_w<<<dim3(3 * 512), dim3(256), 0, stream>>>(Wl, Wr, Wth, Wtl);
    k_in_proj<<<dim3(NN / 16), dim3(256), 0, stream>>>(x, Win, bin, Ah, Al);

    for (int l = 0; l < 3; ++l) {
        k_layer<<<dim3(BBATCH), dim3(512), 0, stream>>>(Ah, Al,
            Wth + (size_t)l * 512 * 256, Wtl + (size_t)l * 512 * 256,
            att + (size_t)l * DD);
    }

    k_readout<<<dim3(BBATCH), dim3(256), 0, stream>>>(Ah, Al, g);
    k_eb<<<dim3(CC), dim3(256), 0, stream>>>(Erecv, Ws1, EB);
    k_head<<<dim3(BBATCH), dim3(256), 0, stream>>>(g, Wr1, br1, Wr2, br2,
                                                   Ws1, bs1, Ws2, bs2, EB, out);
}

// Round 4
// 264.160 us; speedup vs baseline: 2.6128x; 1.7570x over previous
//
#include <hip/hip_runtime.h>

#define BBATCH 1024
#define PP 23      // nodes per frame
#define FF 14
#define DD 256
#define CC 23

typedef __attribute__((ext_vector_type(8))) short bf16x8;
typedef __attribute__((ext_vector_type(4))) float f32x4;

__device__ __forceinline__ short f2bf_rne(float v) {
    unsigned u = __float_as_uint(v);
    unsigned r = (u + 0x7FFFu + ((u >> 16) & 1u)) >> 16;
    return (short)(unsigned short)r;
}
__device__ __forceinline__ float bf2f(short s) {
    return __uint_as_float(((unsigned)(unsigned short)s) << 16);
}

// Packed fragment-major A layout: [frame][mt(2)][ks(8)][lane(64)][e(8)] shorts.
// lane = (row&15) + ((k&31)>>3)*16 ; ks = k>>5 ; e = k&7 ; mt = row>>4.
// One wave-load of lane*8..lane*8+7 = contiguous 1KB = one MFMA A-frag set.

// ---------------- weight prep: packed frag-major Wt hi/lo ----------------
// B layout per layer: [ntile(32)][ks(8)][lane(64)][e(8)], ntile = n>>4.
__global__ __launch_bounds__(256) void k_prep_w(const float* __restrict__ Wl,
    const float* __restrict__ Wr, short* __restrict__ Bh, short* __restrict__ Bl)
{
    __shared__ float ws[DD][16];
    int bid = blockIdx.x;            // l*32 + ntile
    int ll = bid >> 5, ntile = bid & 31;
    int t = threadIdx.x;
    int n0 = ntile * 16;
    const float* W = (n0 < 256) ? (Wl + (size_t)ll * 65536) : (Wr + (size_t)ll * 65536);
    int c0 = n0 & 255;
    for (int kk = t >> 4; kk < DD; kk += 16)
        ws[kk][t & 15] = W[(size_t)kk * 256 + c0 + (t & 15)];
    __syncthreads();
    size_t base = (size_t)bid * 4096;
    for (int idx = t; idx < 4096; idx += 256) {
        int ks = idx >> 9;
        int lane = (idx >> 3) & 63;
        int e = idx & 7;
        int col = lane & 15;
        int k = ks * 32 + ((lane >> 4) << 3) + e;
        float v = ws[k][col];
        short hi = f2bf_rne(v);
        Bh[base + idx] = hi;
        Bl[base + idx] = f2bf_rne(v - bf2f(hi));
    }
}

// ---------------- input projection -> packed bf16 hi/lo ----------------
__global__ __launch_bounds__(256) void k_in_proj(const float* __restrict__ x,
    const float* __restrict__ Win, const float* __restrict__ bin,
    short* __restrict__ Ah, short* __restrict__ Al)
{
    __shared__ float xs[PP][FF];
    int t = threadIdx.x;
    int frame = blockIdx.x;
    for (int idx = t; idx < PP * FF; idx += 256)
        xs[idx / FF][idx % FF] = x[(size_t)frame * PP * FF + idx];
    __syncthreads();
    float w[FF];
#pragma unroll
    for (int f = 0; f < FF; ++f) w[f] = Win[f * DD + t];
    float bb = bin[t];
    int ks = t >> 5, lhi = ((t & 31) >> 3) << 4, e = t & 7;
    size_t fb = (size_t)frame * 8192;
#pragma unroll
    for (int i = 0; i < PP; ++i) {
        float acc = bb;
#pragma unroll
        for (int f = 0; f < FF; ++f) acc = fmaf(xs[i][f], w[f], acc);
        size_t off = fb + ((size_t)((i >> 4) * 8 + ks) << 9) + ((i & 15) + lhi) * 8 + e;
        short hi = f2bf_rne(acc);
        Ah[off] = hi;
        Al[off] = f2bf_rne(acc - bf2f(hi));
    }
}

// ---------------- fused per-frame GATv2 layer ----------------
__global__ __launch_bounds__(512, 4) void k_layer(
    short* __restrict__ Ah, short* __restrict__ Al,
    const short* __restrict__ Bh, const short* __restrict__ Bl,
    const float* __restrict__ att)
{
    __shared__ float sl[PP][DD + 2];     // stride 258: float2-aligned, 2-way banks
    __shared__ float sr[PP][DD + 2];
    __shared__ float S[PP][PP][4];
    __shared__ float satt[DD];

    int t = threadIdx.x;
    int frame = blockIdx.x;
    if (t < DD) satt[t] = att[t];

    int l = t & 63;
    int w = t >> 6;

    // ---- GEMM: wave w owns cols 64w..64w+63; all loads 1KB contiguous ----
    const short* pA_h = Ah + (size_t)frame * 8192 + l * 8;
    const short* pA_l = Al + (size_t)frame * 8192 + l * 8;
    const short* pB_h = Bh + (size_t)(w * 4) * 4096 + l * 8;
    const short* pB_l = Bl + (size_t)(w * 4) * 4096 + l * 8;

    f32x4 acc[2][4];
#pragma unroll
    for (int mt = 0; mt < 2; ++mt)
#pragma unroll
        for (int nt = 0; nt < 4; ++nt) acc[mt][nt] = (f32x4)0.0f;

#pragma unroll
    for (int ks = 0; ks < 8; ++ks) {
        bf16x8 ah0 = *(const bf16x8*)(pA_h + ks * 512);
        bf16x8 ah1 = *(const bf16x8*)(pA_h + (8 + ks) * 512);
        bf16x8 al0 = *(const bf16x8*)(pA_l + ks * 512);
        bf16x8 al1 = *(const bf16x8*)(pA_l + (8 + ks) * 512);
#pragma unroll
        for (int nt = 0; nt < 4; ++nt) {
            bf16x8 bh = *(const bf16x8*)(pB_h + (nt * 8 + ks) * 512);
            bf16x8 bl = *(const bf16x8*)(pB_l + (nt * 8 + ks) * 512);
            acc[0][nt] = __builtin_amdgcn_mfma_f32_16x16x32_bf16(ah0, bh, acc[0][nt], 0, 0, 0);
            acc[0][nt] = __builtin_amdgcn_mfma_f32_16x16x32_bf16(ah0, bl, acc[0][nt], 0, 0, 0);
            acc[0][nt] = __builtin_amdgcn_mfma_f32_16x16x32_bf16(al0, bh, acc[0][nt], 0, 0, 0);
            acc[1][nt] = __builtin_amdgcn_mfma_f32_16x16x32_bf16(ah1, bh, acc[1][nt], 0, 0, 0);
            acc[1][nt] = __builtin_amdgcn_mfma_f32_16x16x32_bf16(ah1, bl, acc[1][nt], 0, 0, 0);
            acc[1][nt] = __builtin_amdgcn_mfma_f32_16x16x32_bf16(al1, bh, acc[1][nt], 0, 0, 0);
        }
    }

    // scatter acc -> LDS hl/hr (f32), drop pad rows
#pragma unroll
    for (int mt = 0; mt < 2; ++mt) {
        int row = mt * 16 + (l >> 4) * 4;
#pragma unroll
        for (int nt = 0; nt < 4; ++nt) {
            int col = w * 64 + nt * 16 + (l & 15);
            float* dst = (col < 256) ? &sl[0][0] : &sr[0][0];
            int cc = col & 255;
#pragma unroll
            for (int r2 = 0; r2 < 4; ++r2)
                if (row + r2 < PP) dst[(row + r2) * (DD + 2) + cc] = acc[mt][nt][r2];
        }
    }
    __syncthreads();

    // ---- scores: thread per (dst i, src j), 4 heads, float2 LDS reads ----
    for (int p = t; p < PP * PP; p += 512) {
        int i = p / PP, j = p - i * PP;
        const float* slj = &sl[j][0];
        const float* sri = &sr[i][0];
        float s0 = 0.f, s1 = 0.f, s2 = 0.f, s3 = 0.f;
#pragma unroll 8
        for (int k2 = 0; k2 < 32; ++k2) {
            int c = k2 * 2;
            float2 l0 = *(const float2*)&slj[c];
            float2 l1 = *(const float2*)&slj[64 + c];
            float2 l2 = *(const float2*)&slj[128 + c];
            float2 l3 = *(const float2*)&slj[192 + c];
            float2 r0 = *(const float2*)&sri[c];
            float2 r1 = *(const float2*)&sri[64 + c];
            float2 r2 = *(const float2*)&sri[128 + c];
            float2 r3 = *(const float2*)&sri[192 + c];
            float2 w0 = *(const float2*)&satt[c];
            float2 w1 = *(const float2*)&satt[64 + c];
            float2 w2 = *(const float2*)&satt[128 + c];
            float2 w3 = *(const float2*)&satt[192 + c];
            float v;
            v = l0.x + r0.x; v = fmaxf(v, 0.2f * v); s0 = fmaf(w0.x, v, s0);
            v = l0.y + r0.y; v = fmaxf(v, 0.2f * v); s0 = fmaf(w0.y, v, s0);
            v = l1.x + r1.x; v = fmaxf(v, 0.2f * v); s1 = fmaf(w1.x, v, s1);
            v = l1.y + r1.y; v = fmaxf(v, 0.2f * v); s1 = fmaf(w1.y, v, s1);
            v = l2.x + r2.x; v = fmaxf(v, 0.2f * v); s2 = fmaf(w2.x, v, s2);
            v = l2.y + r2.y; v = fmaxf(v, 0.2f * v); s2 = fmaf(w2.y, v, s2);
            v = l3.x + r3.x; v = fmaxf(v, 0.2f * v); s3 = fmaf(w3.x, v, s3);
            v = l3.y + r3.y; v = fmaxf(v, 0.2f * v); s3 = fmaf(w3.y, v, s3);
        }
        bool diag = (i == j);
        S[i][j][0] = diag ? -1e30f : s0;
        S[i][j][1] = diag ? -1e30f : s1;
        S[i][j][2] = diag ? -1e30f : s2;
        S[i][j][3] = diag ? -1e30f : s3;
    }
    __syncthreads();

    // ---- softmax over j for each (i, head) ----
    if (t < PP * 4) {
        int i = t >> 2, hh = t & 3;
        float m = -1e30f;
#pragma unroll
        for (int j = 0; j < PP; ++j) m = fmaxf(m, S[i][j][hh]);
        float s = 0.f;
#pragma unroll
        for (int j = 0; j < PP; ++j) s += __expf(S[i][j][hh] - m);
        float inv = 1.f / s;
#pragma unroll
        for (int j = 0; j < PP; ++j) S[i][j][hh] = __expf(S[i][j][hh] - m) * inv;
    }
    __syncthreads();

    // ---- aggregate + residual + elu -> write back packed bf16 hi/lo ----
    int c = t & 255;
    int ip = t >> 8;
    int hh = c >> 6;   // wave-uniform
    float slc[PP];
#pragma unroll
    for (int j = 0; j < PP; ++j) slc[j] = sl[j][c];
    int ks = c >> 5, lhi = ((c & 31) >> 3) << 4, e = c & 7;
    size_t fb = (size_t)frame * 8192;
    for (int i = ip; i < PP; i += 2) {
        float accv = 0.f;
#pragma unroll
        for (int j = 0; j < PP; ++j) accv = fmaf(S[i][j][hh], slc[j], accv);
        size_t off = fb + ((size_t)((i >> 4) * 8 + ks) << 9) + ((i & 15) + lhi) * 8 + e;
        float prev = bf2f(Ah[off]) + bf2f(Al[off]);
        float res = accv + prev;
        float outv = (res > 0.f) ? res : (__expf(res) - 1.f);
        short hi = f2bf_rne(outv);
        Ah[off] = hi;
        Al[off] = f2bf_rne(outv - bf2f(hi));
    }
}

// ---------------- mean readout per frame (packed bf16 hi/lo) ----------------
__global__ __launch_bounds__(256) void k_readout(const short* __restrict__ Ah,
    const short* __restrict__ Al, float* __restrict__ g)
{
    int b = blockIdx.x, t = threadIdx.x;
    int ks = t >> 5, lhi = ((t & 31) >> 3) << 4, e = t & 7;
    size_t fb = (size_t)b * 8192;
    float acc = 0.f;
#pragma unroll
    for (int i = 0; i < PP; ++i) {
        size_t off = fb + ((size_t)((i >> 4) * 8 + ks) << 9) + ((i & 15) + lhi) * 8 + e;
        acc += bf2f(Ah[off]) + bf2f(Al[off]);
    }
    g[b * DD + t] = acc * (1.0f / 23.0f);
}

// ---------------- EB[c] = E_recv[c] @ Ws1[256:512,:] ----------------
__global__ __launch_bounds__(256) void k_eb(const float* __restrict__ E,
    const float* __restrict__ Ws1, float* __restrict__ EB)
{
    int c = blockIdx.x, t = threadIdx.x;
    float acc = 0.f;
    for (int k = 0; k < DD; ++k)
        acc = fmaf(E[c * DD + k], Ws1[(DD + k) * DD + t], acc);
    EB[c * DD + t] = acc;
}

// ---------------- per-graph head ----------------
__global__ __launch_bounds__(256) void k_head(const float* __restrict__ g,
    const float* __restrict__ Wr1, const float* __restrict__ br1,
    const float* __restrict__ Wr2, const float* __restrict__ br2,
    const float* __restrict__ Ws1, const float* __restrict__ bs1,
    const float* __restrict__ Ws2, const float* __restrict__ bs2,
    const float* __restrict__ EB, float* __restrict__ out)
{
    __shared__ float gs[DD], t1[DD], gtop[DD], logits[CC], probs[CC], red[4];
    int b = blockIdx.x, t = threadIdx.x;
    gs[t] = g[b * DD + t];
    __syncthreads();

    float a1 = 0.f, a2 = 0.f;
    for (int k = 0; k < DD; ++k) {
        float gv = gs[k];
        a1 = fmaf(gv, Wr1[k * DD + t], a1);
        a2 = fmaf(gv, Ws1[k * DD + t], a2);
    }
    t1[t] = fmaxf(a1 + br1[t], 0.f);
    gtop[t] = a2 + bs1[t];
    __syncthreads();

    if (t < CC) {
        float acc = br2[t];
        for (int d = 0; d < DD; ++d) acc = fmaf(t1[d], Wr2[d * CC + t], acc);
        logits[t] = acc;
    }
    __syncthreads();
    if (t < CC) {
        float m = -1e30f;
        for (int c = 0; c < CC; ++c) m = fmaxf(m, logits[c]);
        float s = 0.f;
        for (int c = 0; c < CC; ++c) s += __expf(logits[c] - m);
        probs[t] = __expf(logits[t] - m) / s;
    }
    __syncthreads();

    float wd = Ws2[t];
    float gt = gtop[t];
    float acc = 0.f;
#pragma unroll
    for (int c = 0; c < CC; ++c) {
        float s1 = fmaxf(gt + EB[c * DD + t], 0.f);
        acc = fmaf(probs[c], s1, acc);
    }
    acc *= wd;
#pragma unroll
    for (int off = 32; off > 0; off >>= 1) acc += __shfl_down(acc, off, 64);
    if ((t & 63) == 0) red[t >> 6] = acc;
    __syncthreads();
    if (t == 0) out[b] = red[0] + red[1] + red[2] + red[3] + bs2[0];
}

extern "C" void kernel_launch(void* const* d_in, const int* in_sizes, int n_in,
                              void* d_out, int out_size, void* d_ws, size_t ws_size,
                              hipStream_t stream)
{
    const float* x     = (const float*)d_in[0];
    const float* Win   = (const float*)d_in[3];
    const float* bin   = (const float*)d_in[4];
    const float* Wl    = (const float*)d_in[5];
    const float* Wr    = (const float*)d_in[6];
    const float* att   = (const float*)d_in[7];
    const float* Wr1   = (const float*)d_in[8];
    const float* br1   = (const float*)d_in[9];
    const float* Wr2   = (const float*)d_in[10];
    const float* br2   = (const float*)d_in[11];
    const float* Erecv = (const float*)d_in[12];
    const float* Ws1   = (const float*)d_in[13];
    const float* bs1   = (const float*)d_in[14];
    const float* Ws2   = (const float*)d_in[15];
    const float* bs2   = (const float*)d_in[16];
    float* out = (float*)d_out;

    // workspace
    short* Ah = (short*)d_ws;                       // [1024][8192]
    short* Al = Ah + (size_t)1024 * 8192;
    short* Bh = Al + (size_t)1024 * 8192;           // [3][32][4096]
    short* Bl = Bh + (size_t)3 * 131072;
    float* g  = (float*)(Bl + (size_t)3 * 131072);  // [B][DD]
    float* EB = g + (size_t)BBATCH * DD;            // [CC][DD]

    k_prep_w<<<dim3(96), dim3(256), 0, stream>>>(Wl, Wr, Bh, Bl);
    k_in_proj<<<dim3(BBATCH), dim3(256), 0, stream>>>(x, Win, bin, Ah, Al);

    for (int l = 0; l < 3; ++l) {
        k_layer<<<dim3(BBATCH), dim3(512), 0, stream>>>(Ah, Al,
            Bh + (size_t)l * 131072, Bl + (size_t)l * 131072,
            att + (size_t)l * DD);
    }

    k_readout<<<dim3(BBATCH), dim3(256), 0, stream>>>(Ah, Al, g);
    k_eb<<<dim3(CC), dim3(256), 0, stream>>>(Erecv, Ws1, EB);
    k_head<<<dim3(BBATCH), dim3(256), 0, stream>>>(g, Wr1, br1, Wr2, br2,
                                                   Ws1, bs1, Ws2, bs2, EB, out);
}

// Round 5
// 245.927 us; speedup vs baseline: 2.8065x; 1.0741x over previous
//
#include <hip/hip_runtime.h>

#define BBATCH 1024
#define NPAIR 512
#define PP 23      // nodes per frame
#define FF 14
#define DD 256
#define CC 23
#define APAIR 12288   // shorts per pair: 3 mtiles * 8 ks * 512

typedef __attribute__((ext_vector_type(8))) short bf16x8;
typedef __attribute__((ext_vector_type(4))) float f32x4;

#define GLOAD16(gp, lp) __builtin_amdgcn_global_load_lds( \
    (const __attribute__((address_space(1))) void*)(gp),  \
    (__attribute__((address_space(3))) void*)(lp), 16, 0, 0)

__device__ __forceinline__ short f2bf_rne(float v) {
    unsigned u = __float_as_uint(v);
    unsigned r = (u + 0x7FFFu + ((u >> 16) & 1u)) >> 16;
    return (short)(unsigned short)r;
}
__device__ __forceinline__ float bf2f(short s) {
    return __uint_as_float(((unsigned)(unsigned short)s) << 16);
}

// Pair-packed A: [pair][mt(3)][ks(8)][lane(64)][e(8)] shorts.
// row r = f*23 + i (0..45; 46,47 pad-never-written), lane = (r&15) + ((k&31)>>3)*16,
// ks = k>>5, e = k&7, mt = r>>4.

// ---------------- weight prep: packed frag-major Wt hi/lo ----------------
__global__ __launch_bounds__(256) void k_prep_w(const float* __restrict__ Wl,
    const float* __restrict__ Wr, short* __restrict__ Bh, short* __restrict__ Bl)
{
    __shared__ float ws[DD][16];
    int bid = blockIdx.x;            // l*32 + ntile
    int ll = bid >> 5, ntile = bid & 31;
    int t = threadIdx.x;
    int n0 = ntile * 16;
    const float* W = (n0 < 256) ? (Wl + (size_t)ll * 65536) : (Wr + (size_t)ll * 65536);
    int c0 = n0 & 255;
    for (int kk = t >> 4; kk < DD; kk += 16)
        ws[kk][t & 15] = W[(size_t)kk * 256 + c0 + (t & 15)];
    __syncthreads();
    size_t base = (size_t)bid * 4096;
    for (int idx = t; idx < 4096; idx += 256) {
        int ks = idx >> 9;
        int lane = (idx >> 3) & 63;
        int e = idx & 7;
        int col = lane & 15;
        int k = ks * 32 + ((lane >> 4) << 3) + e;
        float v = ws[k][col];
        short hi = f2bf_rne(v);
        Bh[base + idx] = hi;
        Bl[base + idx] = f2bf_rne(v - bf2f(hi));
    }
}

// ---------------- input projection -> pair-packed bf16 hi/lo ----------------
__global__ __launch_bounds__(256) void k_in_proj(const float* __restrict__ x,
    const float* __restrict__ Win, const float* __restrict__ bin,
    short* __restrict__ Ah, short* __restrict__ Al)
{
    __shared__ float xs[PP][FF];
    int t = threadIdx.x;
    int frame = blockIdx.x;
    for (int idx = t; idx < PP * FF; idx += 256)
        xs[idx / FF][idx % FF] = x[(size_t)frame * PP * FF + idx];
    __syncthreads();
    float w[FF];
#pragma unroll
    for (int f = 0; f < FF; ++f) w[f] = Win[f * DD + t];
    float bb = bin[t];
    int ks = t >> 5, lhi = ((t & 31) >> 3) << 4, e = t & 7;
    size_t pb = (size_t)(frame >> 1) * APAIR;
    int r0 = (frame & 1) * PP;
#pragma unroll
    for (int i = 0; i < PP; ++i) {
        float acc = bb;
#pragma unroll
        for (int f = 0; f < FF; ++f) acc = fmaf(xs[i][f], w[f], acc);
        int r = r0 + i;
        size_t off = pb + ((size_t)((r >> 4) * 8 + ks) << 9) + ((r & 15) + lhi) * 8 + e;
        short hi = f2bf_rne(acc);
        Ah[off] = hi;
        Al[off] = f2bf_rne(acc - bf2f(hi));
    }
}

// ---------------- fused 2-frame GATv2 layer ----------------
__global__ __launch_bounds__(512, 4) void k_layer(
    short* __restrict__ Ah, short* __restrict__ Al,
    const short* __restrict__ Bh, const short* __restrict__ Bl,
    const float* __restrict__ att, float* __restrict__ g)
{
    // union region: phase1 = staged A (49152 B); phase2 = sl/sr/S (55952 B)
    __shared__ __align__(16) char smem[55968];
    __shared__ float satt[DD];
    __shared__ float gsum[2][DD];

    short* lsA = (short*)smem;                 // hi [12288], lo at +12288
    float* sl  = (float*)smem;                 // [23][258]
    float* sr  = (float*)(smem + 23744);       // [23][258]
    float* S   = (float*)(smem + 47488);       // [23][23][4]

    int t = threadIdx.x;
    int pair = blockIdx.x;
    size_t pb = (size_t)pair * APAIR;
    if (t < DD) satt[t] = att[t];

    // ---- stage A (hi+lo, 48 KB) into LDS ----
    {
        const short* gAh = Ah + pb + t * 8;
        const short* gAl = Al + pb + t * 8;
#pragma unroll
        for (int pass = 0; pass < 3; ++pass) {
            GLOAD16(gAh + pass * 4096, lsA + pass * 4096 + t * 8);
            GLOAD16(gAl + pass * 4096, lsA + 12288 + pass * 4096 + t * 8);
        }
    }

    int l = t & 63, w = t >> 6;
    const short* pB_h = Bh + (size_t)(w * 4) * 4096 + l * 8;
    const short* pB_l = Bl + (size_t)(w * 4) * 4096 + l * 8;
    const short* lA_h = lsA + l * 8;
    const short* lA_l = lsA + 12288 + l * 8;

    f32x4 acc[3][4];
#pragma unroll
    for (int mt = 0; mt < 3; ++mt)
#pragma unroll
        for (int nt = 0; nt < 4; ++nt) acc[mt][nt] = (f32x4)0.0f;

    __syncthreads();   // staging complete

    // ---- GEMM: M=46(+2 pad), N=512, K=256, hi/lo 3-term ----
#pragma unroll
    for (int ks = 0; ks < 8; ++ks) {
        bf16x8 ah[3], al2[3];
#pragma unroll
        for (int mt = 0; mt < 3; ++mt) {
            ah[mt]  = *(const bf16x8*)(lA_h + (mt * 8 + ks) * 512);
            al2[mt] = *(const bf16x8*)(lA_l + (mt * 8 + ks) * 512);
        }
#pragma unroll
        for (int nt = 0; nt < 4; ++nt) {
            bf16x8 bh = *(const bf16x8*)(pB_h + (nt * 8 + ks) * 512);
            bf16x8 bl = *(const bf16x8*)(pB_l + (nt * 8 + ks) * 512);
#pragma unroll
            for (int mt = 0; mt < 3; ++mt) {
                acc[mt][nt] = __builtin_amdgcn_mfma_f32_16x16x32_bf16(ah[mt], bh, acc[mt][nt], 0, 0, 0);
                acc[mt][nt] = __builtin_amdgcn_mfma_f32_16x16x32_bf16(ah[mt], bl, acc[mt][nt], 0, 0, 0);
                acc[mt][nt] = __builtin_amdgcn_mfma_f32_16x16x32_bf16(al2[mt], bh, acc[mt][nt], 0, 0, 0);
            }
        }
    }
    __syncthreads();   // all waves done reading lsA

    // ---- per-frame attention ----
    for (int f = 0; f < 2; ++f) {
        // scatter this frame's rows from acc -> sl/sr
#pragma unroll
        for (int mt = 0; mt < 3; ++mt) {
            int rbase = mt * 16 + (l >> 4) * 4;
#pragma unroll
            for (int nt = 0; nt < 4; ++nt) {
                int col = w * 64 + nt * 16 + (l & 15);
                float* dst = (col < 256) ? sl : sr;
                int cc = col & 255;
#pragma unroll
                for (int r2 = 0; r2 < 4; ++r2) {
                    int i = rbase + r2 - f * PP;
                    if (0 <= i && i < PP) dst[i * 258 + cc] = acc[mt][nt][r2];
                }
            }
        }
        __syncthreads();

        // scores
        for (int p = t; p < PP * PP; p += 512) {
            int i = p / PP, j = p - i * PP;
            const float* slj = sl + j * 258;
            const float* sri = sr + i * 258;
            float s0 = 0.f, s1 = 0.f, s2 = 0.f, s3 = 0.f;
#pragma unroll 8
            for (int k2 = 0; k2 < 32; ++k2) {
                int c = k2 * 2;
                float2 l0 = *(const float2*)(slj + c);
                float2 l1 = *(const float2*)(slj + 64 + c);
                float2 l2 = *(const float2*)(slj + 128 + c);
                float2 l3 = *(const float2*)(slj + 192 + c);
                float2 r0 = *(const float2*)(sri + c);
                float2 r1 = *(const float2*)(sri + 64 + c);
                float2 r2 = *(const float2*)(sri + 128 + c);
                float2 r3 = *(const float2*)(sri + 192 + c);
                float2 w0 = *(const float2*)(satt + c);
                float2 w1 = *(const float2*)(satt + 64 + c);
                float2 w2 = *(const float2*)(satt + 128 + c);
                float2 w3 = *(const float2*)(satt + 192 + c);
                float v;
                v = l0.x + r0.x; v = fmaxf(v, 0.2f * v); s0 = fmaf(w0.x, v, s0);
                v = l0.y + r0.y; v = fmaxf(v, 0.2f * v); s0 = fmaf(w0.y, v, s0);
                v = l1.x + r1.x; v = fmaxf(v, 0.2f * v); s1 = fmaf(w1.x, v, s1);
                v = l1.y + r1.y; v = fmaxf(v, 0.2f * v); s1 = fmaf(w1.y, v, s1);
                v = l2.x + r2.x; v = fmaxf(v, 0.2f * v); s2 = fmaf(w2.x, v, s2);
                v = l2.y + r2.y; v = fmaxf(v, 0.2f * v); s2 = fmaf(w2.y, v, s2);
                v = l3.x + r3.x; v = fmaxf(v, 0.2f * v); s3 = fmaf(w3.x, v, s3);
                v = l3.y + r3.y; v = fmaxf(v, 0.2f * v); s3 = fmaf(w3.y, v, s3);
            }
            bool diag = (i == j);
            float* Sp = S + (i * PP + j) * 4;
            Sp[0] = diag ? -1e30f : s0;
            Sp[1] = diag ? -1e30f : s1;
            Sp[2] = diag ? -1e30f : s2;
            Sp[3] = diag ? -1e30f : s3;
        }
        __syncthreads();

        // softmax over j for each (i, head)
        if (t < PP * 4) {
            int i = t >> 2, hh = t & 3;
            float m = -1e30f;
#pragma unroll
            for (int j = 0; j < PP; ++j) m = fmaxf(m, S[(i * PP + j) * 4 + hh]);
            float s = 0.f;
#pragma unroll
            for (int j = 0; j < PP; ++j) s += __expf(S[(i * PP + j) * 4 + hh] - m);
            float inv = 1.f / s;
#pragma unroll
            for (int j = 0; j < PP; ++j) {
                float* p = S + (i * PP + j) * 4 + hh;
                *p = __expf(*p - m) * inv;
            }
        }
        __syncthreads();

        // aggregate + residual + elu -> write pair-packed bf16 hi/lo (+ g partial)
        {
            int c = t & 255, ip = t >> 8, hh = c >> 6;
            float slc[PP];
#pragma unroll
            for (int j = 0; j < PP; ++j) slc[j] = sl[j * 258 + c];
            int ksw = c >> 5, lhi = ((c & 31) >> 3) << 4, e = c & 7;
            float fsum = 0.f;
            for (int i = ip; i < PP; i += 2) {
                float accv = 0.f;
#pragma unroll
                for (int j = 0; j < PP; ++j)
                    accv = fmaf(S[(i * PP + j) * 4 + hh], slc[j], accv);
                int r = f * PP + i;
                size_t off = pb + ((size_t)((r >> 4) * 8 + ksw) << 9) + ((r & 15) + lhi) * 8 + e;
                float prev = bf2f(Ah[off]) + bf2f(Al[off]);
                float res = accv + prev;
                float outv = (res > 0.f) ? res : (__expf(res) - 1.f);
                Ah[off] = f2bf_rne(outv);
                Al[off] = f2bf_rne(outv - bf2f(f2bf_rne(outv)));
                fsum += outv;
            }
            if (g) gsum[ip][c] = fsum;
        }
        __syncthreads();   // sl/sr free for next frame; gsum ready

        if (g && t < DD)
            g[(size_t)(pair * 2 + f) * DD + t] = (gsum[0][t] + gsum[1][t]) * (1.0f / 23.0f);
    }
}

// ---------------- EB[c] = E_recv[c] @ Ws1[256:512,:] ----------------
__global__ __launch_bounds__(256) void k_eb(const float* __restrict__ E,
    const float* __restrict__ Ws1, float* __restrict__ EB)
{
    int c = blockIdx.x, t = threadIdx.x;
    float acc = 0.f;
    for (int k = 0; k < DD; ++k)
        acc = fmaf(E[c * DD + k], Ws1[(DD + k) * DD + t], acc);
    EB[c * DD + t] = acc;
}

// ---------------- head: 4 graphs per block ----------------
__global__ __launch_bounds__(256) void k_head(const float* __restrict__ g,
    const float* __restrict__ Wr1, const float* __restrict__ br1,
    const float* __restrict__ Wr2, const float* __restrict__ br2,
    const float* __restrict__ Ws1, const float* __restrict__ bs1,
    const float* __restrict__ Ws2, const float* __restrict__ bs2,
    const float* __restrict__ EB, float* __restrict__ out)
{
    __shared__ float gs[4][DD], t1s[4][DD], gtop[4][DD];
    __shared__ float logits[4][CC], probs[4][CC];
    __shared__ float red[4][4];   // [wave][gg]
    int b0 = blockIdx.x * 4;
    int t = threadIdx.x;
    for (int idx = t; idx < 4 * DD; idx += 256)
        gs[idx >> 8][idx & 255] = g[(size_t)b0 * DD + idx];
    __syncthreads();

    float a1[4] = {0.f, 0.f, 0.f, 0.f}, a2[4] = {0.f, 0.f, 0.f, 0.f};
    for (int k = 0; k < DD; k += 2) {
        float w1a = Wr1[k * DD + t], w1b = Wr1[(k + 1) * DD + t];
        float w2a = Ws1[k * DD + t], w2b = Ws1[(k + 1) * DD + t];
#pragma unroll
        for (int gg = 0; gg < 4; ++gg) {
            float2 gv = *(const float2*)&gs[gg][k];
            a1[gg] = fmaf(gv.x, w1a, a1[gg]);
            a1[gg] = fmaf(gv.y, w1b, a1[gg]);
            a2[gg] = fmaf(gv.x, w2a, a2[gg]);
            a2[gg] = fmaf(gv.y, w2b, a2[gg]);
        }
    }
#pragma unroll
    for (int gg = 0; gg < 4; ++gg) {
        t1s[gg][t] = fmaxf(a1[gg] + br1[t], 0.f);
        gtop[gg][t] = a2[gg] + bs1[t];
    }
    __syncthreads();

    if (t < 4 * CC) {
        int gg = t / CC, c = t - gg * CC;
        float acc = br2[c];
        for (int d = 0; d < DD; ++d) acc = fmaf(t1s[gg][d], Wr2[d * CC + c], acc);
        logits[gg][c] = acc;
    }
    __syncthreads();
    if (t < 4 * CC) {
        int gg = t / CC, c = t - gg * CC;
        float m = -1e30f;
        for (int cc = 0; cc < CC; ++cc) m = fmaxf(m, logits[gg][cc]);
        float s = 0.f;
        for (int cc = 0; cc < CC; ++cc) s += __expf(logits[gg][cc] - m);
        probs[gg][c] = __expf(logits[gg][c] - m) / s;
    }
    __syncthreads();

    float wd = Ws2[t];
    float sacc[4];
#pragma unroll
    for (int gg = 0; gg < 4; ++gg) {
        float gt = gtop[gg][t];
        float acc = 0.f;
#pragma unroll
        for (int c = 0; c < CC; ++c)
            acc = fmaf(probs[gg][c], fmaxf(gt + EB[c * DD + t], 0.f), acc);
        sacc[gg] = acc * wd;
    }
#pragma unroll
    for (int gg = 0; gg < 4; ++gg) {
        float v = sacc[gg];
#pragma unroll
        for (int off = 32; off > 0; off >>= 1) v += __shfl_down(v, off, 64);
        if ((t & 63) == 0) red[t >> 6][gg] = v;
    }
    __syncthreads();
    if (t < 4)
        out[b0 + t] = red[0][t] + red[1][t] + red[2][t] + red[3][t] + bs2[0];
}

extern "C" void kernel_launch(void* const* d_in, const int* in_sizes, int n_in,
                              void* d_out, int out_size, void* d_ws, size_t ws_size,
                              hipStream_t stream)
{
    const float* x     = (const float*)d_in[0];
    const float* Win   = (const float*)d_in[3];
    const float* bin   = (const float*)d_in[4];
    const float* Wl    = (const float*)d_in[5];
    const float* Wr    = (const float*)d_in[6];
    const float* att   = (const float*)d_in[7];
    const float* Wr1   = (const float*)d_in[8];
    const float* br1   = (const float*)d_in[9];
    const float* Wr2   = (const float*)d_in[10];
    const float* br2   = (const float*)d_in[11];
    const float* Erecv = (const float*)d_in[12];
    const float* Ws1   = (const float*)d_in[13];
    const float* bs1   = (const float*)d_in[14];
    const float* Ws2   = (const float*)d_in[15];
    const float* bs2   = (const float*)d_in[16];
    float* out = (float*)d_out;

    short* Ah = (short*)d_ws;                       // [512][12288]
    short* Al = Ah + (size_t)NPAIR * APAIR;
    short* Bh = Al + (size_t)NPAIR * APAIR;         // [3][32][4096]
    short* Bl = Bh + (size_t)3 * 131072;
    float* g  = (float*)(Bl + (size_t)3 * 131072);  // [B][DD]
    float* EB = g + (size_t)BBATCH * DD;            // [CC][DD]

    k_prep_w<<<dim3(96), dim3(256), 0, stream>>>(Wl, Wr, Bh, Bl);
    k_in_proj<<<dim3(BBATCH), dim3(256), 0, stream>>>(x, Win, bin, Ah, Al);

    for (int l = 0; l < 3; ++l) {
        k_layer<<<dim3(NPAIR), dim3(512), 0, stream>>>(Ah, Al,
            Bh + (size_t)l * 131072, Bl + (size_t)l * 131072,
            att + (size_t)l * DD, (l == 2) ? g : nullptr);
    }

    k_eb<<<dim3(CC), dim3(256), 0, stream>>>(Erecv, Ws1, EB);
    k_head<<<dim3(256), dim3(256), 0, stream>>>(g, Wr1, br1, Wr2, br2,
                                                Ws1, bs1, Ws2, bs2, EB, out);
}